// Round 1
// baseline (86.106 us; speedup 1.0000x reference)
//
#include <hip/hip_runtime.h>

#define T_LEN 4096
#define B_SZ 64
#define D_IN 128
#define U_H 256
#define REC_MAXV 0.0625f

typedef __attribute__((ext_vector_type(8))) short short8;
typedef __attribute__((ext_vector_type(4))) float f32x4;

__device__ __forceinline__ short f2bf(float f) {
    unsigned u = __builtin_bit_cast(unsigned, f);
    unsigned r = u + 0x7FFFu + ((u >> 16) & 1u);
    return (short)(r >> 16);
}

// ---------------- kernel 0: h[b][u] = relu(xs[b,T-1,:] . We[u,:] + be[u]) ----
__global__ void k_h(const float* __restrict__ xs, const float* __restrict__ We,
                    const float* __restrict__ be, float* __restrict__ h) {
    int b = blockIdx.x, u = threadIdx.x;
    const f32x4* xr = (const f32x4*)(xs + ((size_t)b * T_LEN + (T_LEN - 1)) * D_IN);
    const f32x4* wr = (const f32x4*)(We + (size_t)u * D_IN);
    float s = 0.f;
#pragma unroll
    for (int i = 0; i < 32; ++i) {
        f32x4 a = xr[i], w = wr[i];
        s += a[0]*w[0] + a[1]*w[1] + a[2]*w[2] + a[3]*w[3];
    }
    s += be[u];
    h[b * U_H + u] = fmaxf(s, 0.f);
}

// ---------------- kernel 1: prep bud, weight fragments, zero loss ------------
// WdF frag (k=K/32 step 0..3, ut=u-tile 0..15): lane l elem j =
//   Wd[ut*16+(l&15)][k*32+8*(l>>4)+j]   (B-operand layout for 16x16x32 mfma)
// WoF frag (k2 0..7, dt 0..7): lane l elem j = Wo[dt*16+(l&15)][k2*32+8*(l>>4)+j]
__global__ void k_prep(const float* __restrict__ Wd, const float* __restrict__ Wo,
                       const float* __restrict__ bd, const float* __restrict__ ud,
                       const float* __restrict__ hbuf, float* __restrict__ bud,
                       short* __restrict__ WdF, short* __restrict__ WoF,
                       float* __restrict__ loss) {
    int gid = blockIdx.x * 256 + threadIdx.x;   // 0..16383
    int u = gid & 255;
    float udc = fminf(fmaxf(ud[u], -REC_MAXV), REC_MAXV);
    bud[gid] = bd[u] + udc * hbuf[gid];
    if (gid == 0) *loss = 0.f;

    if (gid < 4096) {
        int frag = gid >> 6, lane = gid & 63;
        int k = frag >> 4, ut = frag & 15;
        int l15 = lane & 15, hg = lane >> 4;
        const float* src = Wd + (size_t)(ut * 16 + l15) * D_IN + k * 32 + hg * 8;
        short8 v;
#pragma unroll
        for (int j = 0; j < 8; ++j) v[j] = f2bf(src[j]);
        *(short8*)(WdF + (size_t)gid * 8) = v;
    } else if (gid < 8192) {
        int g2 = gid - 4096;
        int frag = g2 >> 6, lane = g2 & 63;
        int k2 = frag >> 3, dt = frag & 7;
        int l15 = lane & 15, hg = lane >> 4;
        const float* src = Wo + (size_t)(dt * 16 + l15) * U_H + k2 * 32 + hg * 8;
        short8 v;
#pragma unroll
        for (int j = 0; j < 8; ++j) v[j] = f2bf(src[j]);
        *(short8*)(WoF + (size_t)g2 * 8) = v;
    }
}

// ---------------- kernel 2: t=0 loss term ------------------------------------
__global__ void k_loss0(const float* __restrict__ xs, const float* __restrict__ hbuf,
                        const float* __restrict__ Wo, const float* __restrict__ bo,
                        float* __restrict__ loss) {
    int b = blockIdx.x, d = threadIdx.x;   // 128 threads
    const f32x4* hr = (const f32x4*)(hbuf + b * U_H);
    const f32x4* wr = (const f32x4*)(Wo + (size_t)d * U_H);
    float s = 0.f;
#pragma unroll
    for (int i = 0; i < 64; ++i) {
        f32x4 a = hr[i], w = wr[i];
        s += a[0]*w[0] + a[1]*w[1] + a[2]*w[2] + a[3]*w[3];
    }
    s += bo[d];
    float x = xs[((size_t)b * T_LEN + T_LEN - 1) * D_IN + d];
    float diff = x - s;
    float v = diff * diff;
#pragma unroll
    for (int o = 32; o > 0; o >>= 1) v += __shfl_down(v, o);
    if ((threadIdx.x & 63) == 0) atomicAdd(loss, v * (1.f / 262144.f));
}

// ---------------- kernel 3: main fused pipeline ------------------------------
// 256 blocks x 512 threads (8 waves). Each wave: 4 tiles of 32 rows.
// LDS: WdF frags [0,64K) + WoF frags [64K,128K) + per-wave dec scratch.
#define DEC_OFF 131072
#define DEC_PITCH 80          // bytes per dec row (32 u * 2B + 16B pad)
#define DEC_WAVE 2560         // 32 rows * 80B
__global__ __launch_bounds__(512, 2) void k_main(
        const float* __restrict__ xs, const float* __restrict__ bud,
        const float* __restrict__ bo, const short* __restrict__ WF,
        float* __restrict__ loss) {
    __shared__ __align__(16) char lds[DEC_OFF + 8 * DEC_WAVE];  // 151552 B
    const int tid = threadIdx.x;

    // stage 128KB of weight fragments
    for (int i = tid; i < 8192; i += 512)
        *(f32x4*)(lds + (size_t)i * 16) = ((const f32x4*)WF)[i];
    __syncthreads();

    const int wave = tid >> 6, lane = tid & 63;
    const int l15 = lane & 15, hg = lane >> 4;
    char* decB = lds + DEC_OFF + wave * DEC_WAVE;
    short* decS = (short*)decB;

    float bov[8];
#pragma unroll
    for (int dt = 0; dt < 8; ++dt) bov[dt] = bo[dt * 16 + l15];

    float lacc = 0.f;

    for (int it = 0; it < 4; ++it) {
        int tile = (blockIdx.x * 8 + wave) * 4 + it;    // 0..8191
        int b = tile >> 7;
        int t0 = (tile & 127) << 5;
        const float* Xb = xs + (((size_t)b << 12) + (size_t)t0) * 128;

        // ---- A fragments: rows t0..t0+31 of xs[b], bf16 ----
        short8 af[2][4];
#pragma unroll
        for (int mt = 0; mt < 2; ++mt)
#pragma unroll
            for (int k = 0; k < 4; ++k) {
                const float* p = Xb + (size_t)(mt * 16 + l15) * 128 + k * 32 + hg * 8;
                f32x4 v0 = *(const f32x4*)p;
                f32x4 v1 = *(const f32x4*)(p + 4);
                short8 a;
                a[0] = f2bf(v0[0]); a[1] = f2bf(v0[1]); a[2] = f2bf(v0[2]); a[3] = f2bf(v0[3]);
                a[4] = f2bf(v1[0]); a[5] = f2bf(v1[1]); a[6] = f2bf(v1[2]); a[7] = f2bf(v1[3]);
                af[mt][k] = a;
            }

        f32x4 oacc[2][8];
#pragma unroll
        for (int mt = 0; mt < 2; ++mt)
#pragma unroll
            for (int dt = 0; dt < 8; ++dt) oacc[mt][dt] = (f32x4){0.f, 0.f, 0.f, 0.f};

        const float* budb = bud + b * 256;

#pragma unroll
        for (int uc = 0; uc < 8; ++uc) {
            // ---- GEMM1: c1[32 rows][32 u] ----
            f32x4 c1[2][2];
#pragma unroll
            for (int mt = 0; mt < 2; ++mt) {
                c1[mt][0] = (f32x4){0.f, 0.f, 0.f, 0.f};
                c1[mt][1] = (f32x4){0.f, 0.f, 0.f, 0.f};
            }
#pragma unroll
            for (int k = 0; k < 4; ++k) {
                short8 b0 = *(const short8*)(lds + (((k * 16 + uc * 2 + 0) << 10) + (lane << 4)));
                short8 b1 = *(const short8*)(lds + (((k * 16 + uc * 2 + 1) << 10) + (lane << 4)));
#pragma unroll
                for (int mt = 0; mt < 2; ++mt) {
                    c1[mt][0] = __builtin_amdgcn_mfma_f32_16x16x32_bf16(af[mt][k], b0, c1[mt][0], 0, 0, 0);
                    c1[mt][1] = __builtin_amdgcn_mfma_f32_16x16x32_bf16(af[mt][k], b1, c1[mt][1], 0, 0, 0);
                }
            }
            // ---- bias + ud*h, relu, -> dec LDS (bf16) ----
            float bud0 = budb[uc * 32 + l15];
            float bud1 = budb[uc * 32 + 16 + l15];
#pragma unroll
            for (int mt = 0; mt < 2; ++mt)
#pragma unroll
                for (int j = 0; j < 4; ++j) {
                    int m = mt * 16 + 4 * hg + j;
                    float v0 = fmaxf(c1[mt][0][j] + bud0, 0.f);
                    float v1 = fmaxf(c1[mt][1][j] + bud1, 0.f);
                    decS[m * (DEC_PITCH / 2) + l15] = f2bf(v0);
                    decS[m * (DEC_PITCH / 2) + 16 + l15] = f2bf(v1);
                }
            // ---- GEMM2 partial: out += dec(32x32u) @ WoT(32u x 128) ----
#pragma unroll
            for (int mt = 0; mt < 2; ++mt) {
                short8 da = *(const short8*)(decB + (mt * 16 + l15) * DEC_PITCH + hg * 16);
#pragma unroll
                for (int dt = 0; dt < 8; ++dt) {
                    short8 bw = *(const short8*)(lds + 65536 + (((uc * 8 + dt) << 10) + (lane << 4)));
                    oacc[mt][dt] = __builtin_amdgcn_mfma_f32_16x16x32_bf16(da, bw, oacc[mt][dt], 0, 0, 0);
                }
            }
        }

        // ---- epilogue: (xs[b,t-1,d] - (out+bo))^2, mask global row t==0 ----
#pragma unroll
        for (int mt = 0; mt < 2; ++mt)
#pragma unroll
            for (int dt = 0; dt < 8; ++dt)
#pragma unroll
                for (int j = 0; j < 4; ++j) {
                    int m = mt * 16 + 4 * hg + j;
                    float outv = oacc[mt][dt][j] + bov[dt];
                    int trow = t0 + m;
                    int mi = (trow > 0) ? (m - 1) : 0;
                    float tgt = Xb[(long)mi * 128 + dt * 16 + l15];
                    float diff = tgt - outv;
                    lacc += (trow > 0) ? diff * diff : 0.f;
                }
    }

#pragma unroll
    for (int o = 32; o > 0; o >>= 1) lacc += __shfl_down(lacc, o);
    if (lane == 0) atomicAdd(loss, lacc * (1.f / 262144.f));
}

extern "C" void kernel_launch(void* const* d_in, const int* in_sizes, int n_in,
                              void* d_out, int out_size, void* d_ws, size_t ws_size,
                              hipStream_t stream) {
    const float* xs = (const float*)d_in[0];
    const float* We = (const float*)d_in[1];
    const float* be = (const float*)d_in[2];
    // d_in[3] = ue (unused: encoder hidden state is always zero)
    const float* Wd = (const float*)d_in[4];
    const float* bd = (const float*)d_in[5];
    const float* ud = (const float*)d_in[6];
    const float* Wo = (const float*)d_in[7];
    const float* bo = (const float*)d_in[8];
    float* loss = (float*)d_out;

    char* ws = (char*)d_ws;
    float* h   = (float*)(ws);              // 65536 B
    float* bud = (float*)(ws + 65536);      // 65536 B
    short* WF  = (short*)(ws + 131072);     // 131072 B (WdF then WoF)
    short* WdF = WF;
    short* WoF = WF + 32768;

    k_h<<<64, 256, 0, stream>>>(xs, We, be, h);
    k_prep<<<64, 256, 0, stream>>>(Wd, Wo, bd, ud, h, bud, WdF, WoF, loss);
    k_loss0<<<64, 128, 0, stream>>>(xs, h, Wo, bo, loss);
    k_main<<<256, 512, 0, stream>>>(xs, bud, bo, WF, loss);
}